// Round 7
// baseline (144.229 us; speedup 1.0000x reference)
//
#include <hip/hip_runtime.h>

typedef _Float16 f16;
typedef _Float16 f16x2 __attribute__((ext_vector_type(2)));
typedef _Float16 f16x4 __attribute__((ext_vector_type(4)));
typedef _Float16 f16x8 __attribute__((ext_vector_type(8)));
typedef float    f32x4 __attribute__((ext_vector_type(4)));
typedef int      i32x4 __attribute__((ext_vector_type(4)));

#define NHEADS 16
#define DK 64
#define BATCH 2
#define SEQ 2048
#define DMODEL 1024
#define MTOT (BATCH*SEQ)          // 4096
#define NQKV (3*DMODEL)           // 3072
#define LOG2E 1.44269504f
#define QSCALE (0.125f * LOG2E)   // fold 1/sqrt(dk) and log2(e) into Q
#define MASKVAL (-10000.0f * LOG2E)

__device__ inline f16x8 ld_f16x8_g(const f16* p) {
  return __builtin_bit_cast(f16x8, *reinterpret_cast<const i32x4*>(p));
}

__device__ inline f16x2 cvt_pk(float a, float b) {
  return __builtin_bit_cast(f16x2, __builtin_amdgcn_cvt_pkrtz(a, b));
}

__device__ inline void gl_lds16(const void* g, void* l) {
  __builtin_amdgcn_global_load_lds(
      (const __attribute__((address_space(1))) unsigned int*)g,
      (__attribute__((address_space(3))) unsigned int*)l, 16, 0, 0);
}

// ---------------- convert f32 -> f16, elementwise (n % 4 == 0) ----------------
__global__ void k_cvt(const float* __restrict__ in, f16* __restrict__ out, int n) {
  int i = (blockIdx.x * blockDim.x + threadIdx.x) * 4;
  if (i >= n) return;
  float4 v = *reinterpret_cast<const float4*>(in + i);
  f16x4 o = { (f16)v.x, (f16)v.y, (f16)v.z, (f16)v.w };
  *reinterpret_cast<f16x4*>(out + i) = o;
}

// ---------------- mask -> additive f32 bias in exp2 domain ----------------
__global__ void k_maskb(const int* __restrict__ mask, float* __restrict__ mb, int n) {
  int i = blockIdx.x * blockDim.x + threadIdx.x;
  if (i < n) mb[i] = mask[i] ? 0.f : MASKVAL;
}

// ------- transpose + convert: in f32 [K][N] -> out f16 [N][K] (K,N % 32 == 0) -------
__global__ void k_tcvt(const float* __restrict__ in, f16* __restrict__ out, int K, int N) {
  __shared__ float tile[32][33];
  int k0 = blockIdx.y * 32, n0 = blockIdx.x * 32;
  int tx = threadIdx.x, ty = threadIdx.y;   // block (32,8)
  #pragma unroll
  for (int i = 0; i < 4; ++i)
    tile[ty + 8*i][tx] = in[(size_t)(k0 + ty + 8*i) * N + n0 + tx];
  __syncthreads();
  #pragma unroll
  for (int i = 0; i < 4; ++i)
    out[(size_t)(n0 + ty + 8*i) * K + k0 + tx] = (f16)tile[tx][ty + 8*i];
}

// ---------------- GEMM: C[M,N] = A[M,K](f16) * Bt[N,K]^T(f16) + bias ----------------
template<int EPI>
__global__ __launch_bounds__(256, 2) void k_gemm(
    const f16* __restrict__ A, const f16* __restrict__ Bt,
    const float* __restrict__ bias,
    f16* __restrict__ qo, f16* __restrict__ ko, f16* __restrict__ vto,
    float* __restrict__ outf, int M, int N, int K)
{
  __shared__ f16 As[128][72];
  __shared__ f16 Bs[128][72];
  const int m0 = blockIdx.y * 128, n0 = blockIdx.x * 128;
  const int t = threadIdx.x;
  const int l = t & 63, w = t >> 6;
  const int wr = w >> 1, wc = w & 1;
  const int lc = l & 15, lk = (l >> 4) * 8;

  f32x4 acc[4][4] = {};

  for (int kt = 0; kt < K; kt += 64) {
    #pragma unroll
    for (int it = 0; it < 4; ++it) {
      int idx = it * 256 + t;
      int row = idx >> 3, c8 = (idx & 7) * 8;
      *reinterpret_cast<i32x4*>(&As[row][c8]) =
        *reinterpret_cast<const i32x4*>(A + (size_t)(m0 + row) * K + kt + c8);
      *reinterpret_cast<i32x4*>(&Bs[row][c8]) =
        *reinterpret_cast<const i32x4*>(Bt + (size_t)(n0 + row) * K + kt + c8);
    }
    __syncthreads();
    #pragma unroll
    for (int ks = 0; ks < 64; ks += 32) {
      f16x8 af[4], bf[4];
      #pragma unroll
      for (int i = 0; i < 4; ++i)
        af[i] = __builtin_bit_cast(f16x8, *reinterpret_cast<i32x4*>(&As[wr*64 + i*16 + lc][ks + lk]));
      #pragma unroll
      for (int j = 0; j < 4; ++j)
        bf[j] = __builtin_bit_cast(f16x8, *reinterpret_cast<i32x4*>(&Bs[wc*64 + j*16 + lc][ks + lk]));
      #pragma unroll
      for (int i = 0; i < 4; ++i)
        #pragma unroll
        for (int j = 0; j < 4; ++j)
          acc[i][j] = __builtin_amdgcn_mfma_f32_16x16x32_f16(af[i], bf[j], acc[i][j], 0, 0, 0);
    }
    __syncthreads();
  }

  const int lr4 = (l >> 4) * 4;   // C/D: row = (l>>4)*4 + r, col = l&15
  #pragma unroll
  for (int i = 0; i < 4; ++i) {
    #pragma unroll
    for (int j = 0; j < 4; ++j) {
      int col = n0 + wc*64 + j*16 + lc;
      float bv = bias[col];
      #pragma unroll
      for (int r = 0; r < 4; ++r) {
        int row = m0 + wr*64 + i*16 + lr4 + r;
        float v = acc[i][j][r] + bv;
        if (EPI == 0) {
          int which = col >> 10, h = (col >> 6) & 15, d = col & 63;
          int b = row >> 11, s = row & (SEQ - 1);
          size_t bh = (size_t)(b * NHEADS + h);
          if (which == 0)      qo[(bh * SEQ + s) * DK + d] = (f16)(v * QSCALE);
          else if (which == 1) ko[(bh * SEQ + s) * DK + d] = (f16)v;
          else {
            // V^T stored with kappa-permuted s within each 64-tile:
            // kappa(k) = (k&32) | ((k&12)<<1) | ((k&16)>>2) | (k&3)
            int sp = (s & ~63) | (s & 32) | ((s & 12) << 1) | ((s & 16) >> 2) | (s & 3);
            vto[(bh * DK + d) * SEQ + sp] = (f16)v;
          }
        } else {
          outf[(size_t)row * N + col] = v;
        }
      }
    }
  }
}

// ---------------- flash attention v7: in-block split-k ----------------
// 1024 blocks x 256 thr = 32 (b,h) * 32 q-blocks of 64.
// 4 waves = 2 q-halves (qh) x 2 k-splits (ks). Wave owns 32 q rows and half the
// k-tiles -> each staged K/V tile read by 2 waves (halved LDS issue vs v4) while
// keeping 1024 blocks resident. Barrier period = 2 tiles (128 k), 2-buf pairs.
// lsum computed by a ones-row MFMA (saves 32 v_add/iter). Split-k merge in LDS.
__global__ __launch_bounds__(256, 4) void k_attn7(
    const f16* __restrict__ Q, const f16* __restrict__ K,
    const f16* __restrict__ Vt, const float* __restrict__ mbias,
    f16* __restrict__ ctx)
{
  __shared__ f16 Kb[2][2][64][64];   // [buf][tile-of-pair][row][col]  32 KB
  __shared__ f16 Vb[2][2][64][64];   // 32 KB

  // XCD-aware remap: bid%8 = XCD; each XCD owns 4 whole heads.
  const int bid = blockIdx.x;
  const int xcd = bid & 7, slot = bid >> 3;        // slot 0..127
  const int bh = xcd * 4 + (slot >> 5);            // 0..31
  const int qb = slot & 31;
  const int b  = bh >> 4, h = bh & (NHEADS - 1);
  const int t = threadIdx.x, l = t & 63, w = t >> 6;
  const int qh = w & 1, ks = w >> 1;
  const int lc = l & 15, g = l >> 4;
  const int q0 = qb * 64 + qh * 32;

  const f16* Qp = Q + (size_t)bh * SEQ * DK;
  const f16* Kp = K + (size_t)bh * SEQ * DK;
  const f16* Vp = Vt + (size_t)bh * DK * SEQ;
  const float* mp = mbias + b * SEQ;

  // Q B-frags: 2 q-tiles (col = q = lc), kept in regs
  f16x8 qf[2][2];
  #pragma unroll
  for (int qt = 0; qt < 2; ++qt)
    #pragma unroll
    for (int s = 0; s < 2; ++s)
      qf[qt][s] = ld_f16x8_g(Qp + (size_t)(q0 + qt*16 + lc) * DK + s*32 + g*8);

  f32x4 o[2][4] = {};            // O^T acc [q-tile][d-tile]
  f32x4 o4[2] = {};              // ones-row acc: elem0 @ g==0 lanes = lsum[q]
  float mrow[2] = {-3e38f, -3e38f};

  // ones A-frag for the lsum row (row 64 of virtual V^T)
  f16x8 af1;
  {
    f16 onev = (lc == 0) ? (f16)1.f : (f16)0.f;
    #pragma unroll
    for (int i = 0; i < 8; ++i) af1[i] = onev;
  }

  const int srow = l >> 3;                 // staging row within 8-row stripe
  const int ssl  = ((l & 7) ^ srow) * 16;  // inverse-swizzled source slot
  const int swz  = (lc & 7) << 4;          // read-side XOR

  auto do_stage = [&](int buf, int jp) {   // stage tile pair {2jp, 2jp+1}
    #pragma unroll
    for (int j2 = 0; j2 < 2; ++j2) {
      int kt = (jp*2 + j2) * 64;
      #pragma unroll
      for (int p = 0; p < 2; ++p) {
        int r = p*32 + w*8 + srow;
        gl_lds16((const char*)Kp + (size_t)(kt + r) * (DK*2) + ssl,
                 &Kb[buf][j2][p*32 + w*8][0]);
        gl_lds16((const char*)Vp + (size_t)r * (SEQ*2) + (size_t)kt*2 + ssl,
                 &Vb[buf][j2][p*32 + w*8][0]);
      }
    }
  };

  constexpr int NP = SEQ / 128;            // 16 periods of 2 tiles
  do_stage(0, 0);

  float4 b4[4];
  #pragma unroll
  for (int c = 0; c < 4; ++c)
    b4[c] = *reinterpret_cast<const float4*>(mp + ks*64 + c*16 + g*4);

  for (int j = 0; j < NP; ++j) {
    __syncthreads();
    if (j + 1 < NP) do_stage((j + 1) & 1, j + 1);
    const int buf = j & 1;

    // --- S^T = K * Q^T + maskbias (rows = k, cols = q), own tile = 2j+ks ---
    f32x4 p[2][4];
    #pragma unroll
    for (int qt = 0; qt < 2; ++qt)
      #pragma unroll
      for (int c = 0; c < 4; ++c)
        p[qt][c] = f32x4{b4[c].x, b4[c].y, b4[c].z, b4[c].w};
    const char* kb = (const char*)&Kb[buf][ks][0][0];
    #pragma unroll
    for (int c = 0; c < 4; ++c) {
      const char* kr = kb + (c*16 + lc) * 128;
      f16x8 k0 = *(const f16x8*)(kr + ((g*16) ^ swz));
      f16x8 k1 = *(const f16x8*)(kr + ((64 + g*16) ^ swz));
      #pragma unroll
      for (int qt = 0; qt < 2; ++qt) {
        p[qt][c] = __builtin_amdgcn_mfma_f32_16x16x32_f16(k0, qf[qt][0], p[qt][c], 0, 0, 0);
        p[qt][c] = __builtin_amdgcn_mfma_f32_16x16x32_f16(k1, qf[qt][1], p[qt][c], 0, 0, 0);
      }
    }

    // preload next period's bias for own k-split
    if (j + 1 < NP) {
      const float* mn = mp + ((j + 1)*2 + ks) * 64;
      #pragma unroll
      for (int c = 0; c < 4; ++c)
        b4[c] = *reinterpret_cast<const float4*>(mn + c*16 + g*4);
    }

    // --- online softmax (defer-max T13, THR=8 in log2 domain) ---
    float mx[2];
    #pragma unroll
    for (int qt = 0; qt < 2; ++qt) {
      f32x4 m4 = p[qt][0];
      #pragma unroll
      for (int c = 1; c < 4; ++c)
        #pragma unroll
        for (int r = 0; r < 4; ++r) m4[r] = fmaxf(m4[r], p[qt][c][r]);
      mx[qt] = fmaxf(fmaxf(m4[0], m4[1]), fmaxf(m4[2], m4[3]));
    }

    if (!__all(mx[0] <= mrow[0] + 8.f && mx[1] <= mrow[1] + 8.f)) {
      #pragma unroll
      for (int qt = 0; qt < 2; ++qt) {
        float v = mx[qt];
        v = fmaxf(v, __shfl_xor(v, 16));
        v = fmaxf(v, __shfl_xor(v, 32));
        float nm = fmaxf(mrow[qt], v);
        float sc = __builtin_amdgcn_exp2f(mrow[qt] - nm);
        mrow[qt] = nm;
        #pragma unroll
        for (int r = 0; r < 4; ++r) o4[qt][r] *= sc;
        #pragma unroll
        for (int dt = 0; dt < 4; ++dt)
          #pragma unroll
          for (int r = 0; r < 4; ++r) o[qt][dt][r] *= sc;
      }
    }

    // --- P = exp2(S - m), pack in-register (row-sum comes from ones-MFMA) ---
    f16x4 h4[2][4];
    #pragma unroll
    for (int qt = 0; qt < 2; ++qt)
      #pragma unroll
      for (int c = 0; c < 4; ++c) {
        f32x4 e;
        #pragma unroll
        for (int r = 0; r < 4; ++r) e[r] = __builtin_amdgcn_exp2f(p[qt][c][r] - mrow[qt]);
        union { f16x2 h2[2]; f16x4 h4v; } u;
        u.h2[0] = cvt_pk(e[0], e[1]);
        u.h2[1] = cvt_pk(e[2], e[3]);
        h4[qt][c] = u.h4v;
      }

    // --- O^T += V^T * P : B-frag is lane-local [h4[2ch] | h4[2ch+1]] ---
    const char* vb = (const char*)&Vb[buf][ks][0][0];
    #pragma unroll
    for (int ch = 0; ch < 2; ++ch) {
      f16x8 pf[2];
      #pragma unroll
      for (int qt = 0; qt < 2; ++qt) {
        union { f16x4 q[2]; f16x8 v8; } upf;
        upf.q[0] = h4[qt][2*ch]; upf.q[1] = h4[qt][2*ch + 1];
        pf[qt] = upf.v8;
      }
      #pragma unroll
      for (int dt = 0; dt < 4; ++dt) {
        const char* vr = vb + (dt*16 + lc) * 128;
        f16x8 vf = *(const f16x8*)(vr + ((ch*64 + g*16) ^ swz));
        #pragma unroll
        for (int qt = 0; qt < 2; ++qt)
          o[qt][dt] = __builtin_amdgcn_mfma_f32_16x16x32_f16(vf, pf[qt], o[qt][dt], 0, 0, 0);
      }
      #pragma unroll
      for (int qt = 0; qt < 2; ++qt)
        o4[qt] = __builtin_amdgcn_mfma_f32_16x16x32_f16(af1, pf[qt], o4[qt], 0, 0, 0);
    }
  }

  // --- split-k merge: ks=1 publishes (m, l, O) via LDS; ks=0 combines+stores ---
  float lown[2];
  #pragma unroll
  for (int qt = 0; qt < 2; ++qt)
    lown[qt] = __shfl(o4[qt][0], lc);      // broadcast column sum from (g=0,lc)

  __syncthreads();
  float* Ob = (float*)&Kb[0][0][0][0];     // [qh*2+qt][64][16] f32 = 32 KB
  float* Ml = (float*)&Vb[0][0][0][0];     // [qh*2+qt][16][2] f32
  if (ks == 1) {
    #pragma unroll
    for (int qt = 0; qt < 2; ++qt) {
      #pragma unroll
      for (int dt = 0; dt < 4; ++dt)
        #pragma unroll
        for (int r = 0; r < 4; ++r)
          Ob[((qh*2 + qt)*64 + dt*16 + g*4 + r)*16 + lc] = o[qt][dt][r];
      if (g == 0) {
        Ml[((qh*2 + qt)*16 + lc)*2 + 0] = mrow[qt];
        Ml[((qh*2 + qt)*16 + lc)*2 + 1] = lown[qt];
      }
    }
  }
  __syncthreads();
  if (ks == 0) {
    #pragma unroll
    for (int qt = 0; qt < 2; ++qt) {
      float mb_ = Ml[((qh*2 + qt)*16 + lc)*2 + 0];
      float lb_ = Ml[((qh*2 + qt)*16 + lc)*2 + 1];
      float m  = fmaxf(mrow[qt], mb_);
      float sa = __builtin_amdgcn_exp2f(mrow[qt] - m);
      float sb = __builtin_amdgcn_exp2f(mb_ - m);
      float inv = 1.f / (lown[qt]*sa + lb_*sb);
      #pragma unroll
      for (int dt = 0; dt < 4; ++dt) {
        f32x4 ov;
        #pragma unroll
        for (int r = 0; r < 4; ++r)
          ov[r] = (o[qt][dt][r]*sa +
                   Ob[((qh*2 + qt)*64 + dt*16 + g*4 + r)*16 + lc]*sb) * inv;
        union { f16x2 h2[2]; f16x4 h4v; } u;
        u.h2[0] = cvt_pk(ov[0], ov[1]);
        u.h2[1] = cvt_pk(ov[2], ov[3]);
        *(f16x4*)(ctx + (size_t)(b*SEQ + q0 + qt*16 + lc) * DMODEL + h*DK + dt*16 + g*4) = u.h4v;
      }
    }
  }
}

extern "C" void kernel_launch(void* const* d_in, const int* in_sizes, int n_in,
                              void* d_out, int out_size, void* d_ws, size_t ws_size,
                              hipStream_t stream) {
  const float* x    = (const float*)d_in[0];
  const int*   mask = (const int*)d_in[1];
  const float* Wqkv = (const float*)d_in[2];
  const float* bqkv = (const float*)d_in[3];
  const float* Wout = (const float*)d_in[4];
  const float* bout = (const float*)d_in[5];
  float* out = (float*)d_out;

  const size_t SZ_X    = (size_t)MTOT * DMODEL * 2;
  const size_t SZ_WQKV = (size_t)NQKV * DMODEL * 2;
  const size_t SZ_WOUT = (size_t)DMODEL * DMODEL * 2;
  const size_t SZ_QKV  = (size_t)BATCH * NHEADS * SEQ * DK * 2;
  const size_t SZ_MB   = (size_t)MTOT * 4 / 2;   // 2*2048 floats = 16KB
  const size_t NEED = SZ_X + SZ_WQKV + SZ_WOUT + 3*SZ_QKV + SZ_X + SZ_MB;
  if (ws_size < NEED) return;

  char* p = (char*)d_ws;
  f16* xh    = (f16*)p; p += SZ_X;
  f16* Wqkvt = (f16*)p; p += SZ_WQKV;
  f16* Woutt = (f16*)p; p += SZ_WOUT;
  f16* Qh    = (f16*)p; p += SZ_QKV;
  f16* Kh    = (f16*)p; p += SZ_QKV;
  f16* Vth   = (f16*)p; p += SZ_QKV;
  f16* ctx   = (f16*)p; p += SZ_X;
  float* mb  = (float*)p; p += SZ_MB;

  k_cvt<<<(MTOT*DMODEL)/(256*4), 256, 0, stream>>>(x, xh, MTOT*DMODEL);
  k_maskb<<<(BATCH*SEQ + 255)/256, 256, 0, stream>>>(mask, mb, BATCH*SEQ);
  k_tcvt<<<dim3(NQKV/32, DMODEL/32), dim3(32,8), 0, stream>>>(Wqkv, Wqkvt, DMODEL, NQKV);
  k_tcvt<<<dim3(DMODEL/32, DMODEL/32), dim3(32,8), 0, stream>>>(Wout, Woutt, DMODEL, DMODEL);

  k_gemm<0><<<dim3(NQKV/128, MTOT/128), 256, 0, stream>>>(
      xh, Wqkvt, bqkv, Qh, Kh, Vth, nullptr, MTOT, NQKV, DMODEL);

  k_attn7<<<32 * 32, 256, 0, stream>>>(Qh, Kh, Vth, mb, ctx);

  k_gemm<1><<<dim3(DMODEL/128, MTOT/128), 256, 0, stream>>>(
      ctx, Woutt, bout, nullptr, nullptr, nullptr, out, MTOT, DMODEL, DMODEL);
}

// Round 8
// 137.320 us; speedup vs baseline: 1.0503x; 1.0503x over previous
//
#include <hip/hip_runtime.h>

typedef _Float16 f16;
typedef _Float16 f16x2 __attribute__((ext_vector_type(2)));
typedef _Float16 f16x4 __attribute__((ext_vector_type(4)));
typedef _Float16 f16x8 __attribute__((ext_vector_type(8)));
typedef float    f32x4 __attribute__((ext_vector_type(4)));
typedef int      i32x4 __attribute__((ext_vector_type(4)));

#define NHEADS 16
#define DK 64
#define BATCH 2
#define SEQ 2048
#define DMODEL 1024
#define MTOT (BATCH*SEQ)          // 4096
#define NQKV (3*DMODEL)           // 3072
#define LOG2E 1.44269504f
#define QSCALE (0.125f * LOG2E)   // fold 1/sqrt(dk) and log2(e) into Q
#define MASKVAL (-10000.0f * LOG2E)

__device__ inline f16x8 ld_f16x8_g(const f16* p) {
  return __builtin_bit_cast(f16x8, *reinterpret_cast<const i32x4*>(p));
}

__device__ inline f16x2 cvt_pk(float a, float b) {
  return __builtin_bit_cast(f16x2, __builtin_amdgcn_cvt_pkrtz(a, b));
}

__device__ inline void gl_lds16(const void* g, void* l) {
  __builtin_amdgcn_global_load_lds(
      (const __attribute__((address_space(1))) unsigned int*)g,
      (__attribute__((address_space(3))) unsigned int*)l, 16, 0, 0);
}

// ---------------- convert f32 -> f16, elementwise (n % 4 == 0) ----------------
__global__ void k_cvt(const float* __restrict__ in, f16* __restrict__ out, int n) {
  int i = (blockIdx.x * blockDim.x + threadIdx.x) * 4;
  if (i >= n) return;
  float4 v = *reinterpret_cast<const float4*>(in + i);
  f16x4 o = { (f16)v.x, (f16)v.y, (f16)v.z, (f16)v.w };
  *reinterpret_cast<f16x4*>(out + i) = o;
}

// ---------------- mask -> additive f32 bias in exp2 domain ----------------
__global__ void k_maskb(const int* __restrict__ mask, float* __restrict__ mb, int n) {
  int i = blockIdx.x * blockDim.x + threadIdx.x;
  if (i < n) mb[i] = mask[i] ? 0.f : MASKVAL;
}

// ------- transpose + convert: in f32 [K][N] -> out f16 [N][K] (K,N % 32 == 0) -------
__global__ void k_tcvt(const float* __restrict__ in, f16* __restrict__ out, int K, int N) {
  __shared__ float tile[32][33];
  int k0 = blockIdx.y * 32, n0 = blockIdx.x * 32;
  int tx = threadIdx.x, ty = threadIdx.y;   // block (32,8)
  #pragma unroll
  for (int i = 0; i < 4; ++i)
    tile[ty + 8*i][tx] = in[(size_t)(k0 + ty + 8*i) * N + n0 + tx];
  __syncthreads();
  #pragma unroll
  for (int i = 0; i < 4; ++i)
    out[(size_t)(n0 + ty + 8*i) * K + k0 + tx] = (f16)tile[tx][ty + 8*i];
}

// ---------------- GEMM: C[M,N] = A[M,K](f16) * Bt[N,K]^T(f16) + bias ----------------
// m97 structure: 128x128 tile, BK=64, global_load_lds width-16 staging into
// LINEAR LDS, inverse-swizzled source + XOR-swizzled fragment reads (T21).
template<int EPI>
__global__ __launch_bounds__(256, 2) void k_gemm(
    const f16* __restrict__ A, const f16* __restrict__ Bt,
    const float* __restrict__ bias,
    f16* __restrict__ qo, f16* __restrict__ ko, f16* __restrict__ vto,
    float* __restrict__ outf, int M, int N, int K)
{
  __shared__ f16 As[128][64];   // linear, 16 KB
  __shared__ f16 Bs[128][64];   // linear, 16 KB
  const int m0 = blockIdx.y * 128, n0 = blockIdx.x * 128;
  const int t = threadIdx.x;
  const int l = t & 63, w = t >> 6;
  const int wr = w >> 1, wc = w & 1;
  const int lc = l & 15, g = l >> 4;
  const int srow = l >> 3;                  // row within wave's 8-row stripe
  const int ssl  = ((l & 7) ^ srow) * 16;   // inverse-swizzled source byte slot
  const int swz  = (lc & 7) << 4;           // read-side XOR

  f32x4 acc[4][4] = {};

  for (int kt = 0; kt < K; kt += 64) {
    __syncthreads();   // previous compute done before overwriting LDS
    #pragma unroll
    for (int it = 0; it < 4; ++it) {
      int row = it*32 + w*8 + srow;          // this lane's LDS row
      gl_lds16((const char*)(A  + (size_t)(m0 + row) * K + kt) + ssl,
               &As[it*32 + w*8][0]);
      gl_lds16((const char*)(Bt + (size_t)(n0 + row) * K + kt) + ssl,
               &Bs[it*32 + w*8][0]);
    }
    __syncthreads();   // drains vmcnt (global_load_lds) + barrier

    #pragma unroll
    for (int ks = 0; ks < 64; ks += 32) {
      f16x8 af[4], bf[4];
      #pragma unroll
      for (int i = 0; i < 4; ++i) {
        const char* ab = (const char*)&As[wr*64 + i*16 + lc][0];
        af[i] = *(const f16x8*)(ab + ((ks*2 + g*16) ^ swz));
      }
      #pragma unroll
      for (int j = 0; j < 4; ++j) {
        const char* bb = (const char*)&Bs[wc*64 + j*16 + lc][0];
        bf[j] = *(const f16x8*)(bb + ((ks*2 + g*16) ^ swz));
      }
      #pragma unroll
      for (int i = 0; i < 4; ++i)
        #pragma unroll
        for (int j = 0; j < 4; ++j)
          acc[i][j] = __builtin_amdgcn_mfma_f32_16x16x32_f16(af[i], bf[j], acc[i][j], 0, 0, 0);
    }
  }

  const int lr4 = g * 4;   // C/D: row = g*4 + r, col = lc
  #pragma unroll
  for (int i = 0; i < 4; ++i) {
    #pragma unroll
    for (int j = 0; j < 4; ++j) {
      int col = n0 + wc*64 + j*16 + lc;
      float bv = bias[col];
      #pragma unroll
      for (int r = 0; r < 4; ++r) {
        int row = m0 + wr*64 + i*16 + lr4 + r;
        float v = acc[i][j][r] + bv;
        if (EPI == 0) {
          int which = col >> 10, h = (col >> 6) & 15, d = col & 63;
          int b = row >> 11, s = row & (SEQ - 1);
          size_t bh = (size_t)(b * NHEADS + h);
          if (which == 0)      qo[(bh * SEQ + s) * DK + d] = (f16)(v * QSCALE);
          else if (which == 1) ko[(bh * SEQ + s) * DK + d] = (f16)v;
          else {
            // V^T stored with kappa-permuted s within each 64-tile:
            // kappa(k) = (k&32) | ((k&12)<<1) | ((k&16)>>2) | (k&3)
            int sp = (s & ~63) | (s & 32) | ((s & 12) << 1) | ((s & 16) >> 2) | (s & 3);
            vto[(bh * DK + d) * SEQ + sp] = (f16)v;
          }
        } else {
          outf[(size_t)row * N + col] = v;
        }
      }
    }
  }
}

// ---------------- flash attention v4 (best: 63.4 us) ----------------
// 1024 blocks = 32 (b,h) * 32 q-blocks of 64; wave owns 16 q rows.
// LDS: K/V double-buffer only (32 KB) -> 4 blocks/CU. P stays in registers:
// PV k-slots relabeled via kappa-permuted V columns so B-frag = lane's own h4 regs.
// Mask folded into QK accumulator init (f32 bias, preloaded one iter ahead).
__global__ __launch_bounds__(256, 4) void k_attn4(
    const f16* __restrict__ Q, const f16* __restrict__ K,
    const f16* __restrict__ Vt, const float* __restrict__ mbias,
    f16* __restrict__ ctx)
{
  __shared__ f16 Kb[2][64][64];
  __shared__ f16 Vb[2][64][64];

  // XCD-aware remap: bid%8 = XCD; each XCD owns 4 whole heads.
  const int bid = blockIdx.x;
  const int xcd = bid & 7, slot = bid >> 3;        // slot 0..127
  const int bh = xcd * 4 + (slot >> 5);            // 0..31
  const int qb = slot & 31;
  const int b  = bh >> 4, h = bh & (NHEADS - 1);
  const int t = threadIdx.x, l = t & 63, w = t >> 6;
  const int lc = l & 15, g = l >> 4;
  const int q0 = qb * 64 + w * 16;

  const f16* Qp = Q + (size_t)bh * SEQ * DK;
  const f16* Kp = K + (size_t)bh * SEQ * DK;
  const f16* Vp = Vt + (size_t)bh * DK * SEQ;
  const float* mp = mbias + b * SEQ;

  // Q B-frags (col = q = lc), kept in regs
  f16x8 qf[2];
  #pragma unroll
  for (int s = 0; s < 2; ++s)
    qf[s] = ld_f16x8_g(Qp + (size_t)(q0 + lc) * DK + s*32 + g*8);

  f32x4 o[4] = {};            // O^T acc per d-tile
  float mrow = -3e38f;
  f32x4 ls4 = {0.f, 0.f, 0.f, 0.f};

  const int srow = l >> 3;                 // staging row within 8-row stripe
  const int ssl  = ((l & 7) ^ srow) * 16;  // inverse-swizzled source slot
  const int swz  = (lc & 7) << 4;          // read-side XOR

  auto do_stage = [&](int buf, int kt) {
    #pragma unroll
    for (int p = 0; p < 2; ++p) {
      int r = p*32 + w*8 + srow;
      gl_lds16((const char*)Kp + (size_t)(kt + r) * (DK*2) + ssl,
               &Kb[buf][p*32 + w*8][0]);
      gl_lds16((const char*)Vp + (size_t)r * (SEQ*2) + (size_t)kt*2 + ssl,
               &Vb[buf][p*32 + w*8][0]);
    }
  };

  constexpr int NT = SEQ / 64;
  do_stage(0, 0);

  float4 b4[4];
  #pragma unroll
  for (int c = 0; c < 4; ++c)
    b4[c] = *reinterpret_cast<const float4*>(mp + c*16 + g*4);

  for (int it = 0; it < NT; ++it) {
    __syncthreads();                         // vmcnt(0)+lgkmcnt(0)+barrier
    if (it + 1 < NT) do_stage((it + 1) & 1, (it + 1) * 64);

    // --- S^T = K * Q^T + maskbias (rows = k, cols = q) ---
    f32x4 p[4];
    #pragma unroll
    for (int c = 0; c < 4; ++c)
      p[c] = f32x4{b4[c].x, b4[c].y, b4[c].z, b4[c].w};
    const char* kb = (const char*)&Kb[it & 1][0][0];
    #pragma unroll
    for (int c = 0; c < 4; ++c) {
      const char* kr = kb + (c*16 + lc) * 128;
      f16x8 k0 = *(const f16x8*)(kr + ((g*16) ^ swz));
      f16x8 k1 = *(const f16x8*)(kr + ((64 + g*16) ^ swz));
      p[c] = __builtin_amdgcn_mfma_f32_16x16x32_f16(k0, qf[0], p[c], 0, 0, 0);
      p[c] = __builtin_amdgcn_mfma_f32_16x16x32_f16(k1, qf[1], p[c], 0, 0, 0);
    }

    // preload next tile's bias (covered by softmax+PV latency)
    if (it + 1 < NT) {
      const float* mn = mp + (it + 1) * 64;
      #pragma unroll
      for (int c = 0; c < 4; ++c)
        b4[c] = *reinterpret_cast<const float4*>(mn + c*16 + g*4);
    }

    // --- online softmax (defer-max T13, THR=8 in log2 domain) ---
    f32x4 m4 = p[0];
    #pragma unroll
    for (int c = 1; c < 4; ++c)
      #pragma unroll
      for (int r = 0; r < 4; ++r) m4[r] = fmaxf(m4[r], p[c][r]);
    float mx = fmaxf(fmaxf(m4[0], m4[1]), fmaxf(m4[2], m4[3]));

    if (!__all(mx <= mrow + 8.f)) {
      mx = fmaxf(mx, __shfl_xor(mx, 16));
      mx = fmaxf(mx, __shfl_xor(mx, 32));
      float nm = fmaxf(mrow, mx);
      float sc = __builtin_amdgcn_exp2f(mrow - nm);
      mrow = nm;
      #pragma unroll
      for (int r = 0; r < 4; ++r) ls4[r] *= sc;
      #pragma unroll
      for (int dt = 0; dt < 4; ++dt)
        #pragma unroll
        for (int r = 0; r < 4; ++r) o[dt][r] *= sc;
    }

    // --- P = exp2(S - m), vector row-sum, pack in-register ---
    f16x4 h4[4];
    #pragma unroll
    for (int c = 0; c < 4; ++c) {
      f32x4 e;
      #pragma unroll
      for (int r = 0; r < 4; ++r) e[r] = __builtin_amdgcn_exp2f(p[c][r] - mrow);
      #pragma unroll
      for (int r = 0; r < 4; ++r) ls4[r] += e[r];
      union { f16x2 h2[2]; f16x4 h4v; } u;
      u.h2[0] = cvt_pk(e[0], e[1]);
      u.h2[1] = cvt_pk(e[2], e[3]);
      h4[c] = u.h4v;
    }

    // --- O^T += V^T * P : B-frag is lane-local [h4[2ch] | h4[2ch+1]] ---
    const char* vb = (const char*)&Vb[it & 1][0][0];
    #pragma unroll
    for (int ch = 0; ch < 2; ++ch) {
      union { f16x4 q[2]; f16x8 v8; } upf;
      upf.q[0] = h4[2*ch]; upf.q[1] = h4[2*ch + 1];
      f16x8 pf = upf.v8;
      #pragma unroll
      for (int dt = 0; dt < 4; ++dt) {
        const char* vr = vb + (dt*16 + lc) * 128;
        f16x8 vf = *(const f16x8*)(vr + ((ch*64 + g*16) ^ swz));
        o[dt] = __builtin_amdgcn_mfma_f32_16x16x32_f16(vf, pf, o[dt], 0, 0, 0);
      }
    }
  }

  // --- finalize ---
  float s = (ls4[0] + ls4[1]) + (ls4[2] + ls4[3]);
  s += __shfl_xor(s, 16);
  s += __shfl_xor(s, 32);
  float inv = 1.f / s;
  #pragma unroll
  for (int dt = 0; dt < 4; ++dt) {
    union { f16x2 h2[2]; f16x4 h4v; } u;
    u.h2[0] = cvt_pk(o[dt][0]*inv, o[dt][1]*inv);
    u.h2[1] = cvt_pk(o[dt][2]*inv, o[dt][3]*inv);
    *(f16x4*)(ctx + (size_t)(b*SEQ + q0 + lc) * DMODEL + h*DK + dt*16 + g*4) = u.h4v;
  }
}

extern "C" void kernel_launch(void* const* d_in, const int* in_sizes, int n_in,
                              void* d_out, int out_size, void* d_ws, size_t ws_size,
                              hipStream_t stream) {
  const float* x    = (const float*)d_in[0];
  const int*   mask = (const int*)d_in[1];
  const float* Wqkv = (const float*)d_in[2];
  const float* bqkv = (const float*)d_in[3];
  const float* Wout = (const float*)d_in[4];
  const float* bout = (const float*)d_in[5];
  float* out = (float*)d_out;

  const size_t SZ_X    = (size_t)MTOT * DMODEL * 2;
  const size_t SZ_WQKV = (size_t)NQKV * DMODEL * 2;
  const size_t SZ_WOUT = (size_t)DMODEL * DMODEL * 2;
  const size_t SZ_QKV  = (size_t)BATCH * NHEADS * SEQ * DK * 2;
  const size_t SZ_MB   = (size_t)MTOT * 4 / 2;   // 2*2048 floats = 16KB
  const size_t NEED = SZ_X + SZ_WQKV + SZ_WOUT + 3*SZ_QKV + SZ_X + SZ_MB;
  if (ws_size < NEED) return;

  char* p = (char*)d_ws;
  f16* xh    = (f16*)p; p += SZ_X;
  f16* Wqkvt = (f16*)p; p += SZ_WQKV;
  f16* Woutt = (f16*)p; p += SZ_WOUT;
  f16* Qh    = (f16*)p; p += SZ_QKV;
  f16* Kh    = (f16*)p; p += SZ_QKV;
  f16* Vth   = (f16*)p; p += SZ_QKV;
  f16* ctx   = (f16*)p; p += SZ_X;
  float* mb  = (float*)p; p += SZ_MB;

  k_cvt<<<(MTOT*DMODEL)/(256*4), 256, 0, stream>>>(x, xh, MTOT*DMODEL);
  k_maskb<<<(BATCH*SEQ + 255)/256, 256, 0, stream>>>(mask, mb, BATCH*SEQ);
  k_tcvt<<<dim3(NQKV/32, DMODEL/32), dim3(32,8), 0, stream>>>(Wqkv, Wqkvt, DMODEL, NQKV);
  k_tcvt<<<dim3(DMODEL/32, DMODEL/32), dim3(32,8), 0, stream>>>(Wout, Woutt, DMODEL, DMODEL);

  k_gemm<0><<<dim3(NQKV/128, MTOT/128), 256, 0, stream>>>(
      xh, Wqkvt, bqkv, Qh, Kh, Vth, nullptr, MTOT, NQKV, DMODEL);

  k_attn4<<<32 * 32, 256, 0, stream>>>(Qh, Kh, Vth, mb, ctx);

  k_gemm<1><<<dim3(DMODEL/128, MTOT/128), 256, 0, stream>>>(
      ctx, Woutt, bout, nullptr, nullptr, nullptr, out, MTOT, DMODEL, DMODEL);
}

// Round 9
// 133.389 us; speedup vs baseline: 1.0813x; 1.0295x over previous
//
#include <hip/hip_runtime.h>

typedef _Float16 f16;
typedef _Float16 f16x2 __attribute__((ext_vector_type(2)));
typedef _Float16 f16x4 __attribute__((ext_vector_type(4)));
typedef _Float16 f16x8 __attribute__((ext_vector_type(8)));
typedef float    f32x4 __attribute__((ext_vector_type(4)));
typedef float    f32x16 __attribute__((ext_vector_type(16)));
typedef int      i32x4 __attribute__((ext_vector_type(4)));

#define NHEADS 16
#define DK 64
#define BATCH 2
#define SEQ 2048
#define DMODEL 1024
#define MTOT (BATCH*SEQ)          // 4096
#define NQKV (3*DMODEL)           // 3072
#define LOG2E 1.44269504f
#define QSCALE (0.125f * LOG2E)   // fold 1/sqrt(dk) and log2(e) into Q
#define MASKVAL (-10000.0f * LOG2E)

__device__ inline f16x8 ld_f16x8_g(const f16* p) {
  return __builtin_bit_cast(f16x8, *reinterpret_cast<const i32x4*>(p));
}

__device__ inline f16x2 cvt_pk(float a, float b) {
  return __builtin_bit_cast(f16x2, __builtin_amdgcn_cvt_pkrtz(a, b));
}

__device__ inline void gl_lds16(const void* g, void* l) {
  __builtin_amdgcn_global_load_lds(
      (const __attribute__((address_space(1))) unsigned int*)g,
      (__attribute__((address_space(3))) unsigned int*)l, 16, 0, 0);
}

// ---------------- convert f32 -> f16, elementwise (n % 4 == 0) ----------------
__global__ void k_cvt(const float* __restrict__ in, f16* __restrict__ out, int n) {
  int i = (blockIdx.x * blockDim.x + threadIdx.x) * 4;
  if (i >= n) return;
  float4 v = *reinterpret_cast<const float4*>(in + i);
  f16x4 o = { (f16)v.x, (f16)v.y, (f16)v.z, (f16)v.w };
  *reinterpret_cast<f16x4*>(out + i) = o;
}

// ---------------- mask -> additive f32 bias in exp2 domain ----------------
__global__ void k_maskb(const int* __restrict__ mask, float* __restrict__ mb, int n) {
  int i = blockIdx.x * blockDim.x + threadIdx.x;
  if (i < n) mb[i] = mask[i] ? 0.f : MASKVAL;
}

// ------- transpose + convert: in f32 [K][N] -> out f16 [N][K] (K,N % 32 == 0) -------
__global__ void k_tcvt(const float* __restrict__ in, f16* __restrict__ out, int K, int N) {
  __shared__ float tile[32][33];
  int k0 = blockIdx.y * 32, n0 = blockIdx.x * 32;
  int tx = threadIdx.x, ty = threadIdx.y;   // block (32,8)
  #pragma unroll
  for (int i = 0; i < 4; ++i)
    tile[ty + 8*i][tx] = in[(size_t)(k0 + ty + 8*i) * N + n0 + tx];
  __syncthreads();
  #pragma unroll
  for (int i = 0; i < 4; ++i)
    out[(size_t)(n0 + ty + 8*i) * K + k0 + tx] = (f16)tile[tx][ty + 8*i];
}

// ---------------- GEMM: C[M,N] = A[M,K](f16) * Bt[N,K]^T(f16) + bias ----------------
// m97 structure: 128x128 tile, BK=64, global_load_lds width-16 staging into
// LINEAR LDS, inverse-swizzled source + XOR-swizzled fragment reads (T21).
template<int EPI>
__global__ __launch_bounds__(256, 2) void k_gemm(
    const f16* __restrict__ A, const f16* __restrict__ Bt,
    const float* __restrict__ bias,
    f16* __restrict__ qo, f16* __restrict__ ko, f16* __restrict__ vto,
    float* __restrict__ outf, int M, int N, int K)
{
  __shared__ f16 As[128][64];   // linear, 16 KB
  __shared__ f16 Bs[128][64];   // linear, 16 KB
  const int m0 = blockIdx.y * 128, n0 = blockIdx.x * 128;
  const int t = threadIdx.x;
  const int l = t & 63, w = t >> 6;
  const int wr = w >> 1, wc = w & 1;
  const int lc = l & 15, g = l >> 4;
  const int srow = l >> 3;                  // row within wave's 8-row stripe
  const int ssl  = ((l & 7) ^ srow) * 16;   // inverse-swizzled source byte slot
  const int swz  = (lc & 7) << 4;           // read-side XOR

  f32x4 acc[4][4] = {};

  for (int kt = 0; kt < K; kt += 64) {
    __syncthreads();   // previous compute done before overwriting LDS
    #pragma unroll
    for (int it = 0; it < 4; ++it) {
      int row = it*32 + w*8 + srow;          // this lane's LDS row
      gl_lds16((const char*)(A  + (size_t)(m0 + row) * K + kt) + ssl,
               &As[it*32 + w*8][0]);
      gl_lds16((const char*)(Bt + (size_t)(n0 + row) * K + kt) + ssl,
               &Bs[it*32 + w*8][0]);
    }
    __syncthreads();   // drains vmcnt (global_load_lds) + barrier

    #pragma unroll
    for (int ks = 0; ks < 64; ks += 32) {
      f16x8 af[4], bf[4];
      #pragma unroll
      for (int i = 0; i < 4; ++i) {
        const char* ab = (const char*)&As[wr*64 + i*16 + lc][0];
        af[i] = *(const f16x8*)(ab + ((ks*2 + g*16) ^ swz));
      }
      #pragma unroll
      for (int j = 0; j < 4; ++j) {
        const char* bb = (const char*)&Bs[wc*64 + j*16 + lc][0];
        bf[j] = *(const f16x8*)(bb + ((ks*2 + g*16) ^ swz));
      }
      #pragma unroll
      for (int i = 0; i < 4; ++i)
        #pragma unroll
        for (int j = 0; j < 4; ++j)
          acc[i][j] = __builtin_amdgcn_mfma_f32_16x16x32_f16(af[i], bf[j], acc[i][j], 0, 0, 0);
    }
  }

  const int lr4 = g * 4;   // C/D: row = g*4 + r, col = lc
  #pragma unroll
  for (int i = 0; i < 4; ++i) {
    #pragma unroll
    for (int j = 0; j < 4; ++j) {
      int col = n0 + wc*64 + j*16 + lc;
      float bv = bias[col];
      #pragma unroll
      for (int r = 0; r < 4; ++r) {
        int row = m0 + wr*64 + i*16 + lr4 + r;
        float v = acc[i][j][r] + bv;
        if (EPI == 0) {
          int which = col >> 10, h = (col >> 6) & 15, d = col & 63;
          int b = row >> 11, s = row & (SEQ - 1);
          size_t bh = (size_t)(b * NHEADS + h);
          if (which == 0)      qo[(bh * SEQ + s) * DK + d] = (f16)(v * QSCALE);
          else if (which == 1) ko[(bh * SEQ + s) * DK + d] = (f16)v;
          else {
            // V^T stored with sigma-permuted s within each 16-tile:
            // sigma(k) = swap bits 2 and 3 of k (involution, matches 32x32 PV B-frag)
            int sp = (s & ~12) | ((s & 4) << 1) | ((s & 8) >> 1);
            vto[(bh * DK + d) * SEQ + sp] = (f16)v;
          }
        } else {
          outf[(size_t)row * N + col] = v;
        }
      }
    }
  }
}

// ---------------- flash attention v8: 32x32 MFMA ----------------
// 512 blocks x 256 thr = 32 (b,h) * 16 q-blocks of 128; wave owns 32 q.
// LDS 32 KB: K/V 2-buf, PAIRED rows [32][256B] (row R = k|k+32) with 16-slot
// XOR swizzle -> 2-way conflicts only. 16 ds_read_b128 per wave-iter serve 32 q
// (half the per-q LDS traffic of v4). S^T via mfma(K,Q): lane holds ONE q with
// 32 k in regs -> scalar softmax. P in-register for PV (V columns bit2<->bit3
// swapped in GEMM epilogue). Mask bias = QK C-init (zero VALU).
__global__ __launch_bounds__(256, 2) void k_attn8(
    const f16* __restrict__ Q, const f16* __restrict__ K,
    const f16* __restrict__ Vt, const float* __restrict__ mbias,
    f16* __restrict__ ctx)
{
  __shared__ f16 Kb[2][32][128];   // row R: k=R (128B) | k=R+32 (128B), swizzled
  __shared__ f16 Vb[2][32][128];   // row R: d=R | d=R+32

  // XCD-aware remap: bid%8 = XCD; each XCD owns 4 whole heads.
  const int bid = blockIdx.x;
  const int xcd = bid & 7, slot = bid >> 3;        // slot 0..63
  const int bh = xcd * 4 + (slot >> 4);            // 0..31
  const int qb = slot & 15;
  const int b  = bh >> 4, h = bh & (NHEADS - 1);
  const int t = threadIdx.x, l = t & 63, w = t >> 6;
  const int r31 = l & 31, hi = l >> 5;
  const int Rm = r31 & 15;
  const int q0 = qb * 128 + w * 32;

  const f16* Qp = Q + (size_t)bh * SEQ * DK;
  const f16* Kp = K + (size_t)bh * SEQ * DK;
  const f16* Vp = Vt + (size_t)bh * DK * SEQ;
  const float* mp = mbias + b * SEQ;

  // Q B-frags: col=q=r31, kdim d = ds*16 + hi*8 + j
  f16x8 qf[4];
  #pragma unroll
  for (int ds = 0; ds < 4; ++ds)
    qf[ds] = ld_f16x8_g(Qp + (size_t)(q0 + r31) * DK + ds*16 + hi*8);

  f32x16 o[2] = {};                 // O^T acc per d-tile (rows d, col q)
  float mrow = -3e38f;
  float lsum = 0.f;

  auto stage = [&](int buf, int kt) {
    #pragma unroll
    for (int c = 0; c < 2; ++c) {
      int Rbase = w*8 + c*4;
      int R = Rbase + (l >> 4);
      int u = (l & 15) ^ (R & 15);
      int off32 = (u >> 3) * 32;
      int byteoff = (u & 7) * 16;
      gl_lds16((const char*)Kp + (size_t)(kt + off32 + R) * (DK*2) + byteoff,
               &Kb[buf][Rbase][0]);
      gl_lds16((const char*)Vp + (size_t)(off32 + R) * (SEQ*2) + (size_t)kt*2 + byteoff,
               &Vb[buf][Rbase][0]);
    }
  };

  constexpr int NT = SEQ / 64;
  stage(0, 0);

  for (int it = 0; it < NT; ++it) {
    __syncthreads();                          // vmcnt(0)+lgkmcnt(0)+barrier
    if (it + 1 < NT) stage((it + 1) & 1, (it + 1) * 64);
    const int kt = it * 64;
    const char* kb = (const char*)&Kb[it & 1][0][0];
    const char* vb = (const char*)&Vb[it & 1][0][0];

    // --- bias -> QK C-init: reg r of tile T holds k=(r&3)+8*(r>>2)+4hi+32T ---
    f32x16 p[2];
    #pragma unroll
    for (int T = 0; T < 2; ++T) {
      const float* bp = mp + kt + T*32 + 4*hi;
      #pragma unroll
      for (int rq = 0; rq < 4; ++rq) {
        float4 bv = *reinterpret_cast<const float4*>(bp + rq*8);
        p[T][rq*4+0] = bv.x; p[T][rq*4+1] = bv.y;
        p[T][rq*4+2] = bv.z; p[T][rq*4+3] = bv.w;
      }
    }

    // --- S^T = K * Q^T + bias; A-frag row = k-row = r31 of tile T ---
    #pragma unroll
    for (int T = 0; T < 2; ++T)
      #pragma unroll
      for (int ds = 0; ds < 4; ++ds) {
        int slotc = T*8 + ds*2 + hi;
        f16x8 kf = *(const f16x8*)(kb + r31*256 + ((slotc ^ Rm) << 4));
        p[T] = __builtin_amdgcn_mfma_f32_32x32x16_f16(kf, qf[ds], p[T], 0, 0, 0);
      }

    // --- softmax: lane owns 1 q, 32 k-values; pair lane (l^32) has other 32 ---
    float mx = p[0][0];
    #pragma unroll
    for (int T = 0; T < 2; ++T)
      #pragma unroll
      for (int r = 0; r < 16; ++r) mx = fmaxf(mx, p[T][r]);
    mx = fmaxf(mx, __shfl_xor(mx, 32));

    if (!__all(mx <= mrow + 8.f)) {           // defer-max (T13), log2 domain
      float nm = fmaxf(mrow, mx);
      float sc = __builtin_amdgcn_exp2f(mrow - nm);
      mrow = nm;
      lsum *= sc;
      #pragma unroll
      for (int dt = 0; dt < 2; ++dt)
        #pragma unroll
        for (int r = 0; r < 16; ++r) o[dt][r] *= sc;
    }

    // --- P = exp2(S - m), pack pairs; partial sums for ILP ---
    f16x2 h2[2][8];
    float s0 = 0.f, s1 = 0.f;
    #pragma unroll
    for (int T = 0; T < 2; ++T)
      #pragma unroll
      for (int rp = 0; rp < 8; ++rp) {
        float e0 = __builtin_amdgcn_exp2f(p[T][2*rp]   - mrow);
        float e1 = __builtin_amdgcn_exp2f(p[T][2*rp+1] - mrow);
        s0 += e0; s1 += e1;
        h2[T][rp] = cvt_pk(e0, e1);
      }
    lsum += s0 + s1;

    // --- O^T += V^T * P : B-frag = own packed regs; kdim-16 index m = T*2+half ---
    #pragma unroll
    for (int T = 0; T < 2; ++T)
      #pragma unroll
      for (int half = 0; half < 2; ++half) {
        union { f16x2 a[4]; f16x8 v8; } pu;
        pu.a[0] = h2[T][half*4+0]; pu.a[1] = h2[T][half*4+1];
        pu.a[2] = h2[T][half*4+2]; pu.a[3] = h2[T][half*4+3];
        int m = T*2 + half;
        #pragma unroll
        for (int dt = 0; dt < 2; ++dt) {
          int slotc = dt*8 + m*2 + hi;
          f16x8 vf = *(const f16x8*)(vb + r31*256 + ((slotc ^ Rm) << 4));
          o[dt] = __builtin_amdgcn_mfma_f32_32x32x16_f16(vf, pu.v8, o[dt], 0, 0, 0);
        }
      }
  }

  // --- finalize: combine pair-lane sums, normalize, store ---
  lsum += __shfl_xor(lsum, 32);
  float inv = 1.f / lsum;
  f16* cp = ctx + (size_t)(b*SEQ + q0 + r31) * DMODEL + h*DK;
  #pragma unroll
  for (int dt = 0; dt < 2; ++dt)
    #pragma unroll
    for (int rq = 0; rq < 4; ++rq) {
      // regs 4rq..4rq+3 -> d = dt*32 + 8*rq + 4*hi + {0..3} (contiguous)
      union { f16x2 h2v[2]; f16x4 h4v; } u;
      u.h2v[0] = cvt_pk(o[dt][4*rq+0]*inv, o[dt][4*rq+1]*inv);
      u.h2v[1] = cvt_pk(o[dt][4*rq+2]*inv, o[dt][4*rq+3]*inv);
      *(f16x4*)(cp + dt*32 + 8*rq + 4*hi) = u.h4v;
    }
}

extern "C" void kernel_launch(void* const* d_in, const int* in_sizes, int n_in,
                              void* d_out, int out_size, void* d_ws, size_t ws_size,
                              hipStream_t stream) {
  const float* x    = (const float*)d_in[0];
  const int*   mask = (const int*)d_in[1];
  const float* Wqkv = (const float*)d_in[2];
  const float* bqkv = (const float*)d_in[3];
  const float* Wout = (const float*)d_in[4];
  const float* bout = (const float*)d_in[5];
  float* out = (float*)d_out;

  const size_t SZ_X    = (size_t)MTOT * DMODEL * 2;
  const size_t SZ_WQKV = (size_t)NQKV * DMODEL * 2;
  const size_t SZ_WOUT = (size_t)DMODEL * DMODEL * 2;
  const size_t SZ_QKV  = (size_t)BATCH * NHEADS * SEQ * DK * 2;
  const size_t SZ_MB   = (size_t)MTOT * 4 / 2;   // 2*2048 floats = 16KB
  const size_t NEED = SZ_X + SZ_WQKV + SZ_WOUT + 3*SZ_QKV + SZ_X + SZ_MB;
  if (ws_size < NEED) return;

  char* p = (char*)d_ws;
  f16* xh    = (f16*)p; p += SZ_X;
  f16* Wqkvt = (f16*)p; p += SZ_WQKV;
  f16* Woutt = (f16*)p; p += SZ_WOUT;
  f16* Qh    = (f16*)p; p += SZ_QKV;
  f16* Kh    = (f16*)p; p += SZ_QKV;
  f16* Vth   = (f16*)p; p += SZ_QKV;
  f16* ctx   = (f16*)p; p += SZ_X;
  float* mb  = (float*)p; p += SZ_MB;

  k_cvt<<<(MTOT*DMODEL)/(256*4), 256, 0, stream>>>(x, xh, MTOT*DMODEL);
  k_maskb<<<(BATCH*SEQ + 255)/256, 256, 0, stream>>>(mask, mb, BATCH*SEQ);
  k_tcvt<<<dim3(NQKV/32, DMODEL/32), dim3(32,8), 0, stream>>>(Wqkv, Wqkvt, DMODEL, NQKV);
  k_tcvt<<<dim3(DMODEL/32, DMODEL/32), dim3(32,8), 0, stream>>>(Wout, Woutt, DMODEL, DMODEL);

  k_gemm<0><<<dim3(NQKV/128, MTOT/128), 256, 0, stream>>>(
      xh, Wqkvt, bqkv, Qh, Kh, Vth, nullptr, MTOT, NQKV, DMODEL);

  k_attn8<<<32 * 16, 256, 0, stream>>>(Qh, Kh, Vth, mb, ctx);

  k_gemm<1><<<dim3(DMODEL/128, MTOT/128), 256, 0, stream>>>(
      ctx, Woutt, bout, nullptr, nullptr, nullptr, out, MTOT, DMODEL, DMODEL);
}